// Round 12
// baseline (337.316 us; speedup 1.0000x reference)
//
#include <hip/hip_runtime.h>
#include <stdint.h>

#define DEV __device__ __forceinline__

typedef __attribute__((ext_vector_type(8))) short short8;
typedef __attribute__((ext_vector_type(8))) unsigned short ushort8;
typedef __attribute__((ext_vector_type(4))) float f32x4;
typedef __attribute__((ext_vector_type(16))) float f32x16;
typedef __attribute__((ext_vector_type(2))) unsigned int uint2v;

DEV unsigned short f2bf(float f) {
  union { float f; uint32_t u; } v; v.f = f;
  uint32_t u = v.u;
  u += 0x7FFFu + ((u >> 16) & 1);  // RNE
  return (unsigned short)(u >> 16);
}
DEV float bf2f(unsigned short s) {
  union { uint32_t u; float f; } v; v.u = ((uint32_t)s) << 16;
  return v.f;
}
DEV float exp2_fast(float x) {
  float r; asm("v_exp_f32 %0, %1" : "=v"(r) : "v"(x)); return r;
}
DEV uint32_t cvt_pk_bf16(float lo, float hi) {
  uint32_t r; asm("v_cvt_pk_bf16_f32 %0, %1, %2" : "=v"(r) : "v"(lo), "v"(hi)); return r;
}

DEV void async_ld16(void* lds, const void* g) {
  __builtin_amdgcn_global_load_lds(
      (const __attribute__((address_space(1))) unsigned int*)g,
      (__attribute__((address_space(3))) unsigned int*)lds, 16, 0, 0);
}

// ---------------- cast fp32 -> bf16 (vectorized) ----------------
__global__ __launch_bounds__(256) void cast_bf16_kernel(
    const float* __restrict__ in, unsigned short* __restrict__ out, int n) {
  int i = (blockIdx.x * 256 + threadIdx.x) * 4;
  if (i >= n) return;
  f32x4 v = *(const f32x4*)(in + i);
  union { unsigned short u[4]; uint2v v2; } o;
#pragma unroll
  for (int j = 0; j < 4; ++j) o.u[j] = f2bf(v[j]);
  *(uint2v*)(out + i) = o.v2;
}

// ------------- transpose + cast: in fp32 [R][C] -> out bf16 [C][R] -------------
__global__ __launch_bounds__(256) void transpose_cast_kernel(
    const float* __restrict__ in, unsigned short* __restrict__ out, int R, int C) {
  __shared__ float tile[32][33];
  const int c0 = blockIdx.x * 32, r0 = blockIdx.y * 32;
  const int tx = threadIdx.x & 31, ty = threadIdx.x >> 5;  // 32 x 8
#pragma unroll
  for (int i = 0; i < 32; i += 8)
    tile[ty + i][tx] = in[(size_t)(r0 + ty + i) * C + c0 + tx];
  __syncthreads();
#pragma unroll
  for (int i = 0; i < 32; i += 8)
    out[(size_t)(c0 + ty + i) * R + r0 + tx] = f2bf(tile[tx][ty + i]);
}

// ---------------- pipelined bf16 GEMM: C[M][N] = A[M][K] * Bt[N][K]^T ----------------
// ROUND-12 single structural change vs r11: TRIPLE-buffered LDS (3 x 48 KB = 144 KB),
// which makes tile kt+2's staging target disjoint from the buffer being read ->
// the mid-tile lgkmcnt(0)+barrier is DELETED (one barrier per K-tile), and the 6
// stage loads spread 3+3 across the two MFMA phases. Safety: the single top barrier
// bounds wave skew to <1 tile, so writers of buf[(kt+2)%3] never coexist with
// readers of that buffer; vmcnt(6) at top proves t_kt landed (in-order completion).
// Everything else byte-identical to r11: 64x64 wave tiles (4Mx2N), per-cluster
// lgkmcnt(0)+sched_barrier, source-side XOR chunk-swizzle (0 conflicts), setprio.
template <int OUT_BF16>
__global__ __launch_bounds__(512, 2) void gemm_bt(
    const unsigned short* __restrict__ A, const unsigned short* __restrict__ Bt,
    void* __restrict__ Cout, int M, int Nn, int K) {
  __shared__ unsigned short As[3][256 * 64];  // 32 KiB x3
  __shared__ unsigned short Bs[3][128 * 64];  // 16 KiB x3 -> 144 KiB
  const int t = threadIdx.x;
  const int lane = t & 63, w = t >> 6;
  const int wr = (w >> 1) * 64;   // 4 M-groups of 64 rows
  const int wc = (w & 1) * 64;    // 2 N-groups of 64 cols
  const int brow = blockIdx.y * 256, bcol = blockIdx.x * 128;
  const int l15 = lane & 15, lk = lane >> 4;
  const int p = l15 & 7;

  f32x4 acc[4][4] = {};

  // A: 4 chunks/thread, B: 2 chunks/thread; issued in two halves (3+3)
  auto stageA = [&](int buf, int ktile, int j0, int j1) {
    const int koff = ktile * 64;
#pragma unroll
    for (int j = j0; j < j1; ++j) {
      const int slot = j * 512 + t;
      const int row = slot >> 3, ch = slot & 7;
      const int sc = ch ^ (row & 7);
      async_ld16(&As[buf][slot * 8], A + (size_t)(brow + row) * K + koff + sc * 8);
    }
  };
  auto stageB = [&](int buf, int ktile, int j0, int j1) {
    const int koff = ktile * 64;
#pragma unroll
    for (int j = j0; j < j1; ++j) {
      const int slot = j * 512 + t;
      const int row = slot >> 3, ch = slot & 7;
      const int sc = ch ^ (row & 7);
      async_ld16(&Bs[buf][slot * 8], Bt + (size_t)(bcol + row) * K + koff + sc * 8);
    }
  };

  const int NT = K / 64;
  stageA(0, 0, 0, 4); stageB(0, 0, 0, 2);
  stageA(1, 1, 0, 4); stageB(1, 1, 0, 2);

  for (int kt = 0; kt < NT; ++kt) {
    const int cur = kt % 3;
    const int nxt = (kt + 2) % 3;
    const bool pre = (kt + 2 < NT);
    if (kt == NT - 1) { asm volatile("s_waitcnt vmcnt(0)" ::: "memory"); }
    else              { asm volatile("s_waitcnt vmcnt(6)" ::: "memory"); }
    __builtin_amdgcn_sched_barrier(0);
    __builtin_amdgcn_s_barrier();
    __builtin_amdgcn_sched_barrier(0);

    // ---- phase A: issue half the prefetch, read khalf0 fragments, 16 MFMA ----
    if (pre) { stageA(nxt, kt + 2, 0, 3); }
    short8 af0[4], bf0[4];
#pragma unroll
    for (int m = 0; m < 4; ++m)
      af0[m] = *(const short8*)&As[cur][(wr + m * 16 + l15) * 64 + (lk ^ p) * 8];
#pragma unroll
    for (int n = 0; n < 4; ++n)
      bf0[n] = *(const short8*)&Bs[cur][(wc + n * 16 + l15) * 64 + (lk ^ p) * 8];
    asm volatile("s_waitcnt lgkmcnt(0)" ::: "memory");
    __builtin_amdgcn_sched_barrier(0);
    __builtin_amdgcn_s_setprio(1);
#pragma unroll
    for (int m = 0; m < 4; ++m)
#pragma unroll
      for (int n = 0; n < 4; ++n)
        acc[m][n] = __builtin_amdgcn_mfma_f32_16x16x32_bf16(af0[m], bf0[n], acc[m][n], 0, 0, 0);
    __builtin_amdgcn_s_setprio(0);

    // ---- phase B: issue the rest of the prefetch, read khalf1 fragments, 16 MFMA ----
    if (pre) { stageA(nxt, kt + 2, 3, 4); stageB(nxt, kt + 2, 0, 2); }
    short8 af1[4], bf1[4];
#pragma unroll
    for (int m = 0; m < 4; ++m)
      af1[m] = *(const short8*)&As[cur][(wr + m * 16 + l15) * 64 + ((4 + lk) ^ p) * 8];
#pragma unroll
    for (int n = 0; n < 4; ++n)
      bf1[n] = *(const short8*)&Bs[cur][(wc + n * 16 + l15) * 64 + ((4 + lk) ^ p) * 8];
    asm volatile("s_waitcnt lgkmcnt(0)" ::: "memory");
    __builtin_amdgcn_sched_barrier(0);
    __builtin_amdgcn_s_setprio(1);
#pragma unroll
    for (int m = 0; m < 4; ++m)
#pragma unroll
      for (int n = 0; n < 4; ++n)
        acc[m][n] = __builtin_amdgcn_mfma_f32_16x16x32_bf16(af1[m], bf1[n], acc[m][n], 0, 0, 0);
    __builtin_amdgcn_s_setprio(0);
  }

#pragma unroll
  for (int m = 0; m < 4; ++m)
#pragma unroll
    for (int n = 0; n < 4; ++n)
#pragma unroll
      for (int j = 0; j < 4; ++j) {
        const int row = brow + wr + m * 16 + lk * 4 + j;  // D: row=(lane>>4)*4+reg
        const int col = bcol + wc + n * 16 + l15;         //    col=lane&15
        if (OUT_BF16)
          ((unsigned short*)Cout)[(size_t)row * Nn + col] = f2bf(acc[m][n][j]);
        else
          ((float*)Cout)[(size_t)row * Nn + col] = acc[m][n][j];
      }
}

// ------------- RoPE + pack: Y bf16 [B*N][6144] -> Qb,Kb [B,H,N,128], Vt [B,H,128,N] -------------
#define QSCALE 0.12751743f
__global__ __launch_bounds__(256) void rope_pack(
    const unsigned short* __restrict__ Y, const int* __restrict__ pos,
    unsigned short* __restrict__ Qb, unsigned short* __restrict__ Kb,
    unsigned short* __restrict__ Vt, int N) {
  __shared__ unsigned short vt[128 * 32];
  const int bh = blockIdx.x, b = bh >> 4, h = bh & 15;
  const int n0 = blockIdx.y * 32;
  const int t = threadIdx.x;
  const int tok = t >> 3, dp0 = (t & 7) * 8;
  const int n = n0 + tok;
  const float p = (float)pos[b * N + n];
  const size_t yb = (size_t)(b * N + n) * 6144 + h * 128;

  ushort8 qlo = *(const ushort8*)&Y[yb + dp0];
  ushort8 qhi = *(const ushort8*)&Y[yb + dp0 + 64];
  ushort8 klo = *(const ushort8*)&Y[yb + 2048 + dp0];
  ushort8 khi = *(const ushort8*)&Y[yb + 2048 + dp0 + 64];
  ushort8 vlo = *(const ushort8*)&Y[yb + 4096 + dp0];
  ushort8 vhi = *(const ushort8*)&Y[yb + 4096 + dp0 + 64];

  ushort8 oql, oqh, okl, okh;
#pragma unroll
  for (int i = 0; i < 8; ++i) {
    const float d = (float)(dp0 + i);
    const float ang = p * exp2f(d * -0.2076205059304601f);
    const float s = sinf(ang), c = cosf(ang);
    const float ql = bf2f(qlo[i]), qh = bf2f(qhi[i]);
    const float kl = bf2f(klo[i]), kh = bf2f(khi[i]);
    oql[i] = f2bf((ql * c - qh * s) * QSCALE);
    oqh[i] = f2bf((qh * c + ql * s) * QSCALE);
    okl[i] = f2bf(kl * c - kh * s);
    okh[i] = f2bf(kh * c + kl * s);
    vt[(dp0 + i) * 32 + tok] = vlo[i];
    vt[(dp0 + 64 + i) * 32 + tok] = vhi[i];
  }
  const size_t qb = ((size_t)bh * N + n) * 128;
  *(ushort8*)&Qb[qb + dp0] = oql;
  *(ushort8*)&Qb[qb + dp0 + 64] = oqh;
  *(ushort8*)&Kb[qb + dp0] = okl;
  *(ushort8*)&Kb[qb + dp0 + 64] = okh;
  __syncthreads();
  const int d = t >> 1, half = t & 1;
  const size_t vdst = (size_t)bh * 128 * N + (size_t)d * N + n0 + half * 16;
  *(ushort8*)&Vt[vdst]     = *(const ushort8*)&vt[d * 32 + half * 16];
  *(ushort8*)&Vt[vdst + 8] = *(const ushort8*)&vt[d * 32 + half * 16 + 8];
}

// ------------- causal flash attention: 8 waves/block, block-shared LDS K/V -------------
// CONSTANT-WORK PAIRING: block c hosts q-chunk c (waves 0-3) and chunk 15-c (waves 4-7);
// per-block compute = 68 tile-wave-units for every block. One kv sweep serves both.
__global__ __launch_bounds__(512, 2) void flash_attn8(
    const unsigned short* __restrict__ Qb, const unsigned short* __restrict__ Kb,
    const unsigned short* __restrict__ Vt, unsigned short* __restrict__ Ao, int N) {
  __shared__ unsigned short Ks[2][32 * 128];   // [kv][d], 8 KiB each
  __shared__ unsigned short Vs[2][128 * 32];   // [d][kv], 8 KiB each
  const int t = threadIdx.x, lane = t & 63, w = t >> 6;
  const int bh = blockIdx.x, b = bh >> 4, h = bh & 15;
  const int c = blockIdx.y;                    // 0..7
  const int qchunk = (w < 4) ? c : (15 - c);
  const int q0 = qchunk * 128 + (w & 3) * 32;
  const int l31 = lane & 31, hi = lane >> 5;
  const size_t base = (size_t)bh * N * 128;
  const size_t vbase = (size_t)bh * 128 * N;
  const int Twave = q0 >> 5;
  const int Tblk = (15 - c) * 4 + 4;

  const int krow = t >> 4, kch = (t & 15) ^ (krow & 7);
  const int vrow = t >> 2, vch = (t & 3) ^ (vrow & 3);

  auto stage = [&](int tt, int buf) {
    const int kv0 = tt * 32;
    async_ld16(&Ks[buf][t * 8], Kb + base + (size_t)(kv0 + krow) * 128 + kch * 8);
    async_ld16(&Vs[buf][t * 8], Vt + vbase + (size_t)vrow * N + kv0 + vch * 8);
  };

  short8 qf[8];
#pragma unroll
  for (int s = 0; s < 8; ++s)
    qf[s] = *(const short8*)&Qb[base + (size_t)(q0 + l31) * 128 + s * 16 + hi * 8];

  f32x16 acc0 = {}, acc1 = {}, acc2 = {}, acc3 = {};
  float m_run = -1e30f, l_run = 0.f;

  stage(0, 0);
  stage(1, 1);

  for (int tt = 0; tt < Tblk; ++tt) {
    const int cur = tt & 1;
    if (tt < Tblk - 1) { asm volatile("s_waitcnt vmcnt(2)" ::: "memory"); }
    else               { asm volatile("s_waitcnt vmcnt(0)" ::: "memory"); }
    __builtin_amdgcn_sched_barrier(0);
    __builtin_amdgcn_s_barrier();

    if (tt <= Twave) {
      const int kv0 = tt * 32;
      const bool masked = (tt == Twave);

      short8 kf[8];
#pragma unroll
      for (int s = 0; s < 8; ++s)
        kf[s] = *(const short8*)&Ks[cur][l31 * 128 + ((2 * s + hi) ^ (l31 & 7)) * 8];
      short8 vf[8];
#pragma unroll
      for (int cc = 0; cc < 2; ++cc)
#pragma unroll
        for (int dblk = 0; dblk < 4; ++dblk) {
          const int row = dblk * 32 + l31;
          vf[cc * 4 + dblk] = *(const short8*)&Vs[cur][row * 32 + ((2 * cc + hi) ^ (row & 3)) * 8];
        }

      f32x16 st = {};
      __builtin_amdgcn_s_setprio(1);
#pragma unroll
      for (int s = 0; s < 8; ++s)
        st = __builtin_amdgcn_mfma_f32_32x32x16_bf16(kf[s], qf[s], st, 0, 0, 0);
      __builtin_amdgcn_s_setprio(0);

      if (masked) {
        const int qg = q0 + l31;
#pragma unroll
        for (int r = 0; r < 16; ++r) {
          const int kvg = kv0 + (r & 3) + 8 * ((r >> 2) & 1) + 16 * (r >> 3) + 4 * hi;
          st[r] = (kvg > qg) ? -1e30f : st[r];
        }
      }
      float a0 = fmaxf(st[0], st[1]),  a1 = fmaxf(st[2], st[3]),
            a2 = fmaxf(st[4], st[5]),  a3 = fmaxf(st[6], st[7]),
            a4 = fmaxf(st[8], st[9]),  a5 = fmaxf(st[10], st[11]),
            a6 = fmaxf(st[12], st[13]), a7 = fmaxf(st[14], st[15]);
      a0 = fmaxf(a0, a1); a2 = fmaxf(a2, a3); a4 = fmaxf(a4, a5); a6 = fmaxf(a6, a7);
      a0 = fmaxf(a0, a2); a4 = fmaxf(a4, a6);
      float mt = fmaxf(a0, a4);
      mt = fmaxf(mt, __shfl_xor(mt, 32));

      float m_new = fmaxf(m_run, mt);
      const bool defer = __all(mt - m_run <= 8.f);  // T13
      if (defer) {
        m_new = m_run;
      } else {
        const float alpha = exp2_fast(m_run - m_new);
        l_run *= alpha;
#pragma unroll
        for (int r = 0; r < 16; ++r) {
          acc0[r] *= alpha; acc1[r] *= alpha; acc2[r] *= alpha; acc3[r] *= alpha;
        }
      }
      m_run = m_new;

#pragma unroll
      for (int r = 0; r < 16; ++r) st[r] = exp2_fast(st[r] - m_new);
      float s0 = (st[0] + st[1]) + (st[2] + st[3]), s1 = (st[4] + st[5]) + (st[6] + st[7]);
      float s2 = (st[8] + st[9]) + (st[10] + st[11]), s3 = (st[12] + st[13]) + (st[14] + st[15]);
      float lsum = (s0 + s1) + (s2 + s3);
      lsum += __shfl_xor(lsum, 32);
      l_run += lsum;

      short8 pB0, pB1;
#pragma unroll
      for (int cc = 0; cc < 2; ++cc) {
        const int o = cc * 8;
        const uint32_t P01 = cvt_pk_bf16(st[o + 0], st[o + 1]);
        const uint32_t P23 = cvt_pk_bf16(st[o + 2], st[o + 3]);
        const uint32_t P45 = cvt_pk_bf16(st[o + 4], st[o + 5]);
        const uint32_t P67 = cvt_pk_bf16(st[o + 6], st[o + 7]);
        const uint32_t S01 = (uint32_t)__shfl_xor((int)P01, 32);
        const uint32_t S23 = (uint32_t)__shfl_xor((int)P23, 32);
        const uint32_t S45 = (uint32_t)__shfl_xor((int)P45, 32);
        const uint32_t S67 = (uint32_t)__shfl_xor((int)P67, 32);
        union { uint32_t ww[4]; short8 s8; } u;
        u.ww[0] = hi ? S45 : P01;
        u.ww[1] = hi ? S67 : P23;
        u.ww[2] = hi ? P45 : S01;
        u.ww[3] = hi ? P67 : S23;
        if (cc == 0) pB0 = u.s8; else pB1 = u.s8;
      }

      __builtin_amdgcn_s_setprio(1);
      acc0 = __builtin_amdgcn_mfma_f32_32x32x16_bf16(vf[0], pB0, acc0, 0, 0, 0);
      acc1 = __builtin_amdgcn_mfma_f32_32x32x16_bf16(vf[1], pB0, acc1, 0, 0, 0);
      acc2 = __builtin_amdgcn_mfma_f32_32x32x16_bf16(vf[2], pB0, acc2, 0, 0, 0);
      acc3 = __builtin_amdgcn_mfma_f32_32x32x16_bf16(vf[3], pB0, acc3, 0, 0, 0);
      acc0 = __builtin_amdgcn_mfma_f32_32x32x16_bf16(vf[4], pB1, acc0, 0, 0, 0);
      acc1 = __builtin_amdgcn_mfma_f32_32x32x16_bf16(vf[5], pB1, acc1, 0, 0, 0);
      acc2 = __builtin_amdgcn_mfma_f32_32x32x16_bf16(vf[6], pB1, acc2, 0, 0, 0);
      acc3 = __builtin_amdgcn_mfma_f32_32x32x16_bf16(vf[7], pB1, acc3, 0, 0, 0);
      __builtin_amdgcn_s_setprio(0);
    }

    asm volatile("s_waitcnt lgkmcnt(0)" ::: "memory");
    __builtin_amdgcn_sched_barrier(0);
    __builtin_amdgcn_s_barrier();
    if (tt + 2 < Tblk) stage(tt + 2, cur);
  }

  const float inv = 1.f / l_run;
  const size_t orow = (size_t)(b * N + q0 + l31) * 2048 + h * 128;
#pragma unroll
  for (int r = 0; r < 16; r += 2) {
    const int doff = (r & 3) + 8 * ((r >> 2) & 1) + 16 * (r >> 3) + 4 * hi;
    *(uint32_t*)&Ao[orow + 0  + doff] = cvt_pk_bf16(acc0[r] * inv, acc0[r + 1] * inv);
    *(uint32_t*)&Ao[orow + 32 + doff] = cvt_pk_bf16(acc1[r] * inv, acc1[r + 1] * inv);
    *(uint32_t*)&Ao[orow + 64 + doff] = cvt_pk_bf16(acc2[r] * inv, acc2[r + 1] * inv);
    *(uint32_t*)&Ao[orow + 96 + doff] = cvt_pk_bf16(acc3[r] * inv, acc3[r + 1] * inv);
  }
}

extern "C" void kernel_launch(void* const* d_in, const int* in_sizes, int n_in,
                              void* d_out, int out_size, void* d_ws, size_t ws_size,
                              hipStream_t stream) {
  const float* x      = (const float*)d_in[0];
  const int*   pos    = (const int*)d_in[1];
  const float* Wqkv   = (const float*)d_in[2];
  const float* Wproj  = (const float*)d_in[3];
  float* out = (float*)d_out;

  const int N = 2048, C = 2048;
  const int M = 2 * N;

  char* ws = (char*)d_ws;
  unsigned short* Xb      = (unsigned short*)(ws + 0);            // 16 MiB, reused as Ao
  unsigned short* Wqkv_t  = (unsigned short*)(ws + 16777216);     // 24 MiB
  unsigned short* Wproj_t = (unsigned short*)(ws + 41943040);     // 8 MiB
  unsigned short* Y       = (unsigned short*)(ws + 50331648);     // 48 MiB
  unsigned short* Qb      = (unsigned short*)(ws + 100663296);    // 16 MiB
  unsigned short* Kb      = (unsigned short*)(ws + 117440512);    // 16 MiB
  unsigned short* Vt      = (unsigned short*)(ws + 134217728);    // 16 MiB
  unsigned short* Ao = Xb;

  cast_bf16_kernel<<<(M * C) / 1024, 256, 0, stream>>>(x, Xb, M * C);
  transpose_cast_kernel<<<dim3(3 * C / 32, C / 32), 256, 0, stream>>>(Wqkv, Wqkv_t, C, 3 * C);
  transpose_cast_kernel<<<dim3(C / 32, C / 32), 256, 0, stream>>>(Wproj, Wproj_t, C, C);
  gemm_bt<1><<<dim3(3 * C / 128, M / 256), 512, 0, stream>>>(Xb, Wqkv_t, Y, M, 3 * C, C);
  rope_pack<<<dim3(32, N / 32), 256, 0, stream>>>(Y, pos, Qb, Kb, Vt, N);
  flash_attn8<<<dim3(32, 8), 512, 0, stream>>>(Qb, Kb, Vt, Ao, N);
  gemm_bt<0><<<dim3(C / 128, M / 256), 512, 0, stream>>>(Ao, Wproj_t, out, M, C, C);
}

// Round 13
// 291.298 us; speedup vs baseline: 1.1580x; 1.1580x over previous
//
#include <hip/hip_runtime.h>
#include <stdint.h>

#define DEV __device__ __forceinline__

typedef __attribute__((ext_vector_type(8))) short short8;
typedef __attribute__((ext_vector_type(8))) unsigned short ushort8;
typedef __attribute__((ext_vector_type(4))) float f32x4;
typedef __attribute__((ext_vector_type(16))) float f32x16;
typedef __attribute__((ext_vector_type(2))) unsigned int uint2v;

DEV unsigned short f2bf(float f) {
  union { float f; uint32_t u; } v; v.f = f;
  uint32_t u = v.u;
  u += 0x7FFFu + ((u >> 16) & 1);  // RNE
  return (unsigned short)(u >> 16);
}
DEV float bf2f(unsigned short s) {
  union { uint32_t u; float f; } v; v.u = ((uint32_t)s) << 16;
  return v.f;
}
DEV float exp2_fast(float x) {
  float r; asm("v_exp_f32 %0, %1" : "=v"(r) : "v"(x)); return r;
}
DEV uint32_t cvt_pk_bf16(float lo, float hi) {
  uint32_t r; asm("v_cvt_pk_bf16_f32 %0, %1, %2" : "=v"(r) : "v"(lo), "v"(hi)); return r;
}

DEV void async_ld16(void* lds, const void* g) {
  __builtin_amdgcn_global_load_lds(
      (const __attribute__((address_space(1))) unsigned int*)g,
      (__attribute__((address_space(3))) unsigned int*)lds, 16, 0, 0);
}

// ---------------- cast fp32 -> bf16 (vectorized) ----------------
__global__ __launch_bounds__(256) void cast_bf16_kernel(
    const float* __restrict__ in, unsigned short* __restrict__ out, int n) {
  int i = (blockIdx.x * 256 + threadIdx.x) * 4;
  if (i >= n) return;
  f32x4 v = *(const f32x4*)(in + i);
  union { unsigned short u[4]; uint2v v2; } o;
#pragma unroll
  for (int j = 0; j < 4; ++j) o.u[j] = f2bf(v[j]);
  *(uint2v*)(out + i) = o.v2;
}

// ------------- transpose + cast: in fp32 [R][C] -> out bf16 [C][R] -------------
__global__ __launch_bounds__(256) void transpose_cast_kernel(
    const float* __restrict__ in, unsigned short* __restrict__ out, int R, int C) {
  __shared__ float tile[32][33];
  const int c0 = blockIdx.x * 32, r0 = blockIdx.y * 32;
  const int tx = threadIdx.x & 31, ty = threadIdx.x >> 5;  // 32 x 8
#pragma unroll
  for (int i = 0; i < 32; i += 8)
    tile[ty + i][tx] = in[(size_t)(r0 + ty + i) * C + c0 + tx];
  __syncthreads();
#pragma unroll
  for (int i = 0; i < 32; i += 8)
    out[(size_t)(c0 + ty + i) * R + r0 + tx] = f2bf(tile[tx][ty + i]);
}

// ---------------- pipelined bf16 GEMM (EXACT r11: proven 117.7 us QKV) ----------------
// 256x128 tile, BK=64, 8 waves, 4Mx2N 64x64 wave tiles. Double-buffered LDS, 2-deep
// prefetch, counted vmcnt + raw s_barrier, stage between the two MFMA clusters,
// source-side XOR chunk-swizzle (0 conflicts measured).
template <int OUT_BF16>
__global__ __launch_bounds__(512, 2) void gemm_bt(
    const unsigned short* __restrict__ A, const unsigned short* __restrict__ Bt,
    void* __restrict__ Cout, int M, int Nn, int K) {
  __shared__ unsigned short As[2][256 * 64];  // 64 KiB
  __shared__ unsigned short Bs[2][128 * 64];  // 32 KiB
  const int t = threadIdx.x;
  const int lane = t & 63, w = t >> 6;
  const int wr = (w >> 1) * 64;   // 4 M-groups of 64 rows
  const int wc = (w & 1) * 64;    // 2 N-groups of 64 cols
  const int brow = blockIdx.y * 256, bcol = blockIdx.x * 128;
  const int l15 = lane & 15, lk = lane >> 4;
  const int p = l15 & 7;

  f32x4 acc[4][4] = {};

  auto stage = [&](int buf, int ktile) {
    const int koff = ktile * 64;
#pragma unroll
    for (int j = 0; j < 4; ++j) {
      const int slot = j * 512 + t;
      const int row = slot >> 3, ch = slot & 7;
      const int sc = ch ^ (row & 7);
      async_ld16(&As[buf][slot * 8], A + (size_t)(brow + row) * K + koff + sc * 8);
    }
#pragma unroll
    for (int j = 0; j < 2; ++j) {
      const int slot = j * 512 + t;
      const int row = slot >> 3, ch = slot & 7;
      const int sc = ch ^ (row & 7);
      async_ld16(&Bs[buf][slot * 8], Bt + (size_t)(bcol + row) * K + koff + sc * 8);
    }
  };

  const int NT = K / 64;
  stage(0, 0);
  stage(1, 1);

  for (int kt = 0; kt < NT; ++kt) {
    const int cur = kt & 1;
    if (kt == NT - 1) { asm volatile("s_waitcnt vmcnt(0)" ::: "memory"); }
    else              { asm volatile("s_waitcnt vmcnt(6)" ::: "memory"); }
    __builtin_amdgcn_sched_barrier(0);
    __builtin_amdgcn_s_barrier();

    short8 af0[4], af1[4], bf0[4], bf1[4];
#pragma unroll
    for (int m = 0; m < 4; ++m) {
      const int row = wr + m * 16 + l15;
      af0[m] = *(const short8*)&As[cur][row * 64 + (lk ^ p) * 8];
      af1[m] = *(const short8*)&As[cur][row * 64 + ((4 + lk) ^ p) * 8];
    }
#pragma unroll
    for (int n = 0; n < 4; ++n) {
      const int row = wc + n * 16 + l15;
      bf0[n] = *(const short8*)&Bs[cur][row * 64 + (lk ^ p) * 8];
      bf1[n] = *(const short8*)&Bs[cur][row * 64 + ((4 + lk) ^ p) * 8];
    }

    // MFMA cluster ks=0
    __builtin_amdgcn_s_setprio(1);
#pragma unroll
    for (int m = 0; m < 4; ++m)
#pragma unroll
      for (int n = 0; n < 4; ++n)
        acc[m][n] = __builtin_amdgcn_mfma_f32_16x16x32_bf16(af0[m], bf0[n], acc[m][n], 0, 0, 0);
    __builtin_amdgcn_s_setprio(0);

    asm volatile("s_waitcnt lgkmcnt(0)" ::: "memory");
    __builtin_amdgcn_sched_barrier(0);
    __builtin_amdgcn_s_barrier();
    if (kt + 2 < NT) stage(cur, kt + 2);

    // MFMA cluster ks=1 (overlaps the just-issued prefetch)
    __builtin_amdgcn_s_setprio(1);
#pragma unroll
    for (int m = 0; m < 4; ++m)
#pragma unroll
      for (int n = 0; n < 4; ++n)
        acc[m][n] = __builtin_amdgcn_mfma_f32_16x16x32_bf16(af1[m], bf1[n], acc[m][n], 0, 0, 0);
    __builtin_amdgcn_s_setprio(0);
  }

#pragma unroll
  for (int m = 0; m < 4; ++m)
#pragma unroll
    for (int n = 0; n < 4; ++n)
#pragma unroll
      for (int j = 0; j < 4; ++j) {
        const int row = brow + wr + m * 16 + lk * 4 + j;  // D: row=(lane>>4)*4+reg
        const int col = bcol + wc + n * 16 + l15;         //    col=lane&15
        if (OUT_BF16)
          ((unsigned short*)Cout)[(size_t)row * Nn + col] = f2bf(acc[m][n][j]);
        else
          ((float*)Cout)[(size_t)row * Nn + col] = acc[m][n][j];
      }
}

// ------------- RoPE + pack: Y bf16 [B*N][6144] -> Qb,Kb [B,H,N,128], Vt [B,H,128,N] -------------
#define QSCALE 0.12751743f
__global__ __launch_bounds__(256) void rope_pack(
    const unsigned short* __restrict__ Y, const int* __restrict__ pos,
    unsigned short* __restrict__ Qb, unsigned short* __restrict__ Kb,
    unsigned short* __restrict__ Vt, int N) {
  __shared__ unsigned short vt[128 * 32];
  const int bh = blockIdx.x, b = bh >> 4, h = bh & 15;
  const int n0 = blockIdx.y * 32;
  const int t = threadIdx.x;
  const int tok = t >> 3, dp0 = (t & 7) * 8;
  const int n = n0 + tok;
  const float p = (float)pos[b * N + n];
  const size_t yb = (size_t)(b * N + n) * 6144 + h * 128;

  ushort8 qlo = *(const ushort8*)&Y[yb + dp0];
  ushort8 qhi = *(const ushort8*)&Y[yb + dp0 + 64];
  ushort8 klo = *(const ushort8*)&Y[yb + 2048 + dp0];
  ushort8 khi = *(const ushort8*)&Y[yb + 2048 + dp0 + 64];
  ushort8 vlo = *(const ushort8*)&Y[yb + 4096 + dp0];
  ushort8 vhi = *(const ushort8*)&Y[yb + 4096 + dp0 + 64];

  ushort8 oql, oqh, okl, okh;
#pragma unroll
  for (int i = 0; i < 8; ++i) {
    const float d = (float)(dp0 + i);
    const float ang = p * exp2f(d * -0.2076205059304601f);
    const float s = sinf(ang), c = cosf(ang);
    const float ql = bf2f(qlo[i]), qh = bf2f(qhi[i]);
    const float kl = bf2f(klo[i]), kh = bf2f(khi[i]);
    oql[i] = f2bf((ql * c - qh * s) * QSCALE);
    oqh[i] = f2bf((qh * c + ql * s) * QSCALE);
    okl[i] = f2bf(kl * c - kh * s);
    okh[i] = f2bf(kh * c + kl * s);
    vt[(dp0 + i) * 32 + tok] = vlo[i];
    vt[(dp0 + 64 + i) * 32 + tok] = vhi[i];
  }
  const size_t qb = ((size_t)bh * N + n) * 128;
  *(ushort8*)&Qb[qb + dp0] = oql;
  *(ushort8*)&Qb[qb + dp0 + 64] = oqh;
  *(ushort8*)&Kb[qb + dp0] = okl;
  *(ushort8*)&Kb[qb + dp0 + 64] = okh;
  __syncthreads();
  const int d = t >> 1, half = t & 1;
  const size_t vdst = (size_t)bh * 128 * N + (size_t)d * N + n0 + half * 16;
  *(ushort8*)&Vt[vdst]     = *(const ushort8*)&vt[d * 32 + half * 16];
  *(ushort8*)&Vt[vdst + 8] = *(const ushort8*)&vt[d * 32 + half * 16 + 8];
}

// ------------- causal flash attention: 4 waves/block, CU-paired chunks -------------
// Grid 32 bh x 16 chunks = 512 blocks (256 threads each, 32 KB LDS -> multi-block/CU).
// Chunk permutation: perm[y] = y<8 ? 15-y : y-8, so blocks y and y+8 (256 apart in
// dispatch order -> same CU under round-robin) carry chunks summing to 15 ->
// constant ~68 tile-wave-units per CU; heavy chunks dispatch FIRST.
// All 4 waves of a block own tiles of the SAME chunk (Twave spread <=3) -> every
// wave computes in essentially every step of its sweep; cross-block co-residency
// supplies the second wave per SIMD that the old paired design lost late-sweep.
// Per-wave math, swizzle, vmcnt discipline identical to the proven r9 kernel.
__global__ __launch_bounds__(256, 2) void flash_attn4(
    const unsigned short* __restrict__ Qb, const unsigned short* __restrict__ Kb,
    const unsigned short* __restrict__ Vt, unsigned short* __restrict__ Ao, int N) {
  __shared__ unsigned short Ks[2][32 * 128];   // [kv][d], 8 KiB each
  __shared__ unsigned short Vs[2][128 * 32];   // [d][kv], 8 KiB each
  const int t = threadIdx.x, lane = t & 63, w = t >> 6;          // 4 waves
  const int bh = blockIdx.x, b = bh >> 4, h = bh & 15;
  const int y = blockIdx.y;
  const int cc = (y < 8) ? (15 - y) : (y - 8);   // heavy chunks first; y,y+8 sum to 15
  const int q0 = cc * 128 + w * 32;
  const int l31 = lane & 31, hi = lane >> 5;
  const size_t base = (size_t)bh * N * 128;
  const size_t vbase = (size_t)bh * 128 * N;
  const int Twave = 4 * cc + w;     // last tile this wave needs
  const int Tblk = 4 * cc + 4;      // block sweep length

  auto stage = [&](int tt, int buf) {
    const int kv0 = tt * 32;
#pragma unroll
    for (int j = 0; j < 2; ++j) {   // K: 32x128 shorts = 512 chunks, 2/thread
      const int slot = j * 256 + t;
      const int krow = slot >> 4, kch = (slot & 15) ^ (krow & 7);
      async_ld16(&Ks[buf][slot * 8], Kb + base + (size_t)(kv0 + krow) * 128 + kch * 8);
    }
#pragma unroll
    for (int j = 0; j < 2; ++j) {   // V: 128x32 shorts = 512 chunks, 2/thread
      const int slot = j * 256 + t;
      const int vrow = slot >> 2, vch = (slot & 3) ^ (vrow & 3);
      async_ld16(&Vs[buf][slot * 8], Vt + vbase + (size_t)vrow * N + kv0 + vch * 8);
    }
  };

  short8 qf[8];
#pragma unroll
  for (int s = 0; s < 8; ++s)
    qf[s] = *(const short8*)&Qb[base + (size_t)(q0 + l31) * 128 + s * 16 + hi * 8];

  f32x16 acc0 = {}, acc1 = {}, acc2 = {}, acc3 = {};
  float m_run = -1e30f, l_run = 0.f;

  stage(0, 0);
  stage(1, 1);

  for (int tt = 0; tt < Tblk; ++tt) {
    const int cur = tt & 1;
    if (tt < Tblk - 1) { asm volatile("s_waitcnt vmcnt(4)" ::: "memory"); }
    else               { asm volatile("s_waitcnt vmcnt(0)" ::: "memory"); }
    __builtin_amdgcn_sched_barrier(0);
    __builtin_amdgcn_s_barrier();

    if (tt <= Twave) {
      const int kv0 = tt * 32;
      const bool masked = (tt == Twave);

      short8 kf[8];
#pragma unroll
      for (int s = 0; s < 8; ++s)
        kf[s] = *(const short8*)&Ks[cur][l31 * 128 + ((2 * s + hi) ^ (l31 & 7)) * 8];
      short8 vf[8];
#pragma unroll
      for (int c2 = 0; c2 < 2; ++c2)
#pragma unroll
        for (int dblk = 0; dblk < 4; ++dblk) {
          const int row = dblk * 32 + l31;
          vf[c2 * 4 + dblk] = *(const short8*)&Vs[cur][row * 32 + ((2 * c2 + hi) ^ (row & 3)) * 8];
        }

      f32x16 st = {};
      __builtin_amdgcn_s_setprio(1);
#pragma unroll
      for (int s = 0; s < 8; ++s)
        st = __builtin_amdgcn_mfma_f32_32x32x16_bf16(kf[s], qf[s], st, 0, 0, 0);
      __builtin_amdgcn_s_setprio(0);

      if (masked) {
        const int qg = q0 + l31;
#pragma unroll
        for (int r = 0; r < 16; ++r) {
          const int kvg = kv0 + (r & 3) + 8 * ((r >> 2) & 1) + 16 * (r >> 3) + 4 * hi;
          st[r] = (kvg > qg) ? -1e30f : st[r];
        }
      }
      float a0 = fmaxf(st[0], st[1]),  a1 = fmaxf(st[2], st[3]),
            a2 = fmaxf(st[4], st[5]),  a3 = fmaxf(st[6], st[7]),
            a4 = fmaxf(st[8], st[9]),  a5 = fmaxf(st[10], st[11]),
            a6 = fmaxf(st[12], st[13]), a7 = fmaxf(st[14], st[15]);
      a0 = fmaxf(a0, a1); a2 = fmaxf(a2, a3); a4 = fmaxf(a4, a5); a6 = fmaxf(a6, a7);
      a0 = fmaxf(a0, a2); a4 = fmaxf(a4, a6);
      float mt = fmaxf(a0, a4);
      mt = fmaxf(mt, __shfl_xor(mt, 32));

      float m_new = fmaxf(m_run, mt);
      const bool defer = __all(mt - m_run <= 8.f);  // T13
      if (defer) {
        m_new = m_run;
      } else {
        const float alpha = exp2_fast(m_run - m_new);
        l_run *= alpha;
#pragma unroll
        for (int r = 0; r < 16; ++r) {
          acc0[r] *= alpha; acc1[r] *= alpha; acc2[r] *= alpha; acc3[r] *= alpha;
        }
      }
      m_run = m_new;

#pragma unroll
      for (int r = 0; r < 16; ++r) st[r] = exp2_fast(st[r] - m_new);
      float s0 = (st[0] + st[1]) + (st[2] + st[3]), s1 = (st[4] + st[5]) + (st[6] + st[7]);
      float s2 = (st[8] + st[9]) + (st[10] + st[11]), s3 = (st[12] + st[13]) + (st[14] + st[15]);
      float lsum = (s0 + s1) + (s2 + s3);
      lsum += __shfl_xor(lsum, 32);
      l_run += lsum;

      short8 pB0, pB1;
#pragma unroll
      for (int c2 = 0; c2 < 2; ++c2) {
        const int o = c2 * 8;
        const uint32_t P01 = cvt_pk_bf16(st[o + 0], st[o + 1]);
        const uint32_t P23 = cvt_pk_bf16(st[o + 2], st[o + 3]);
        const uint32_t P45 = cvt_pk_bf16(st[o + 4], st[o + 5]);
        const uint32_t P67 = cvt_pk_bf16(st[o + 6], st[o + 7]);
        const uint32_t S01 = (uint32_t)__shfl_xor((int)P01, 32);
        const uint32_t S23 = (uint32_t)__shfl_xor((int)P23, 32);
        const uint32_t S45 = (uint32_t)__shfl_xor((int)P45, 32);
        const uint32_t S67 = (uint32_t)__shfl_xor((int)P67, 32);
        union { uint32_t ww[4]; short8 s8; } u;
        u.ww[0] = hi ? S45 : P01;
        u.ww[1] = hi ? S67 : P23;
        u.ww[2] = hi ? P45 : S01;
        u.ww[3] = hi ? P67 : S23;
        if (c2 == 0) pB0 = u.s8; else pB1 = u.s8;
      }

      __builtin_amdgcn_s_setprio(1);
      acc0 = __builtin_amdgcn_mfma_f32_32x32x16_bf16(vf[0], pB0, acc0, 0, 0, 0);
      acc1 = __builtin_amdgcn_mfma_f32_32x32x16_bf16(vf[1], pB0, acc1, 0, 0, 0);
      acc2 = __builtin_amdgcn_mfma_f32_32x32x16_bf16(vf[2], pB0, acc2, 0, 0, 0);
      acc3 = __builtin_amdgcn_mfma_f32_32x32x16_bf16(vf[3], pB0, acc3, 0, 0, 0);
      acc0 = __builtin_amdgcn_mfma_f32_32x32x16_bf16(vf[4], pB1, acc0, 0, 0, 0);
      acc1 = __builtin_amdgcn_mfma_f32_32x32x16_bf16(vf[5], pB1, acc1, 0, 0, 0);
      acc2 = __builtin_amdgcn_mfma_f32_32x32x16_bf16(vf[6], pB1, acc2, 0, 0, 0);
      acc3 = __builtin_amdgcn_mfma_f32_32x32x16_bf16(vf[7], pB1, acc3, 0, 0, 0);
      __builtin_amdgcn_s_setprio(0);
    }

    // all waves done reading buf[cur] -> safe to restage it
    asm volatile("s_waitcnt lgkmcnt(0)" ::: "memory");
    __builtin_amdgcn_sched_barrier(0);
    __builtin_amdgcn_s_barrier();
    if (tt + 2 < Tblk) stage(tt + 2, cur);
  }

  const float inv = 1.f / l_run;
  const size_t orow = (size_t)(b * N + q0 + l31) * 2048 + h * 128;
#pragma unroll
  for (int r = 0; r < 16; r += 2) {
    const int doff = (r & 3) + 8 * ((r >> 2) & 1) + 16 * (r >> 3) + 4 * hi;
    *(uint32_t*)&Ao[orow + 0  + doff] = cvt_pk_bf16(acc0[r] * inv, acc0[r + 1] * inv);
    *(uint32_t*)&Ao[orow + 32 + doff] = cvt_pk_bf16(acc1[r] * inv, acc1[r + 1] * inv);
    *(uint32_t*)&Ao[orow + 64 + doff] = cvt_pk_bf16(acc2[r] * inv, acc2[r + 1] * inv);
    *(uint32_t*)&Ao[orow + 96 + doff] = cvt_pk_bf16(acc3[r] * inv, acc3[r + 1] * inv);
  }
}

extern "C" void kernel_launch(void* const* d_in, const int* in_sizes, int n_in,
                              void* d_out, int out_size, void* d_ws, size_t ws_size,
                              hipStream_t stream) {
  const float* x      = (const float*)d_in[0];
  const int*   pos    = (const int*)d_in[1];
  const float* Wqkv   = (const float*)d_in[2];
  const float* Wproj  = (const float*)d_in[3];
  float* out = (float*)d_out;

  const int N = 2048, C = 2048;
  const int M = 2 * N;

  char* ws = (char*)d_ws;
  unsigned short* Xb      = (unsigned short*)(ws + 0);            // 16 MiB, reused as Ao
  unsigned short* Wqkv_t  = (unsigned short*)(ws + 16777216);     // 24 MiB
  unsigned short* Wproj_t = (unsigned short*)(ws + 41943040);     // 8 MiB
  unsigned short* Y       = (unsigned short*)(ws + 50331648);     // 48 MiB
  unsigned short* Qb      = (unsigned short*)(ws + 100663296);    // 16 MiB
  unsigned short* Kb      = (unsigned short*)(ws + 117440512);    // 16 MiB
  unsigned short* Vt      = (unsigned short*)(ws + 134217728);    // 16 MiB
  unsigned short* Ao = Xb;

  cast_bf16_kernel<<<(M * C) / 1024, 256, 0, stream>>>(x, Xb, M * C);
  transpose_cast_kernel<<<dim3(3 * C / 32, C / 32), 256, 0, stream>>>(Wqkv, Wqkv_t, C, 3 * C);
  transpose_cast_kernel<<<dim3(C / 32, C / 32), 256, 0, stream>>>(Wproj, Wproj_t, C, C);
  gemm_bt<1><<<dim3(3 * C / 128, M / 256), 512, 0, stream>>>(Xb, Wqkv_t, Y, M, 3 * C, C);
  rope_pack<<<dim3(32, N / 32), 256, 0, stream>>>(Y, pos, Qb, Kb, Vt, N);
  flash_attn4<<<dim3(32, 16), 256, 0, stream>>>(Qb, Kb, Vt, Ao, N);
  gemm_bt<0><<<dim3(C / 128, M / 256), 512, 0, stream>>>(Ao, Wproj_t, out, M, C, C);
}